// Round 1
// baseline (1770.999 us; speedup 1.0000x reference)
//
#include <hip/hip_runtime.h>
#include <hip/hip_bf16.h>
#include <math.h>

#define BB 8
#define LL 64
#define DD 256
#define VV 4096
#define RR 512           // BB*LL
#define K3 768

// workspace layout (float offsets)
#define WS_ZE      0
#define WS_ZEU3    (WS_ZE + RR*DD)          // 131072
#define WS_WCT     (WS_ZEU3 + RR*DD)        // 262144  (256 x 768, [c][k])
#define WS_XSA0    (WS_WCT + DD*K3)         // 458752
#define WS_XSA1    (WS_XSA0 + RR*DD)
#define WS_EMIT    (WS_XSA1 + RR*DD)
#define WS_YVEC    (WS_EMIT + RR*DD)
#define WS_X0VEC   (WS_YVEC + DD)
#define WS_YK      (WS_X0VEC + DD)
#define WS_YLOG    (WS_YK + DD)
#define WS_YLSE    (WS_YLOG + VV)
#define WS_SEL     (WS_YLSE + 8)
#define WS_HPART   (WS_SEL + RR*4)
#define WS_LSE     (WS_HPART + 1024*8*2)
#define WS_TGT     (WS_LSE + 1024)

__device__ __forceinline__ float waveSum(float v) {
#pragma unroll
  for (int o = 32; o > 0; o >>= 1) v += __shfl_xor(v, o, 64);
  return v;
}

__device__ __forceinline__ float blockSum256(float v) {
  __shared__ float red[4];
  int lane = threadIdx.x & 63, w = threadIdx.x >> 6;
  v = waveSum(v);
  __syncthreads();
  if (lane == 0) red[w] = v;
  __syncthreads();
  return red[0] + red[1] + red[2] + red[3];
}

// --- normalize rows: ze (512), yvec, x0vec -------------------------------
__global__ __launch_bounds__(256) void k_norm_rows(
    const int* __restrict__ z, const float* __restrict__ embed,
    const float* __restrict__ initw, float* __restrict__ ws) {
  int r = blockIdx.x, d = threadIdx.x;
  float a; float* dst;
  if (r < RR) { int tok = z[r]; a = embed[tok * DD + d]; dst = ws + WS_ZE + r * DD; }
  else if (r == RR) { a = embed[d]; dst = ws + WS_YVEC; }
  else { a = initw[d * 16]; dst = ws + WS_X0VEC; }
  float s  = blockSum256(a);
  float sq = blockSum256(a * a);
  float mean = s * (1.0f / DD);
  float var = fmaxf((sq - (float)DD * mean * mean) * (1.0f / (DD - 1)), 0.0f);
  dst[d] = a / (1e-5f + sqrtf(var));
}

// --- build combined transposed weights WcT[c][0:768] = [Tw;TwT;Cw]/3 -----
__global__ __launch_bounds__(256) void k_build_w(
    const float* __restrict__ tw, const float* __restrict__ cw,
    float* __restrict__ wct) {
  int c = blockIdx.x, k = threadIdx.x;
  const float inv3 = 1.0f / 3.0f;
  wct[c * K3 + k]       = tw[k * DD + c] * inv3;  // x[l-1] @ Tw
  wct[c * K3 + 256 + k] = tw[c * DD + k] * inv3;  // x[l+1] @ Tw^T
  wct[c * K3 + 512 + k] = cw[k * DD + c] * inv3;  // x[l]   @ Cw
}

// --- yk = yvec @ xkd_w^T + xkd_b -----------------------------------------
__global__ __launch_bounds__(256) void k_yk(
    const float* __restrict__ xkdw, const float* __restrict__ xkdb,
    float* __restrict__ ws) {
  int d = threadIdx.x;
  __shared__ float y[DD];
  y[d] = ws[WS_YVEC + d];
  __syncthreads();
  float acc = xkdb[d];
  for (int k = 0; k < DD; k++) acc += y[k] * xkdw[d * DD + k];
  ws[WS_YK + d] = acc;
}

// --- broadcast x0vec into xsa buffer 0 -----------------------------------
__global__ __launch_bounds__(256) void k_bcast(float* __restrict__ ws) {
  int r = blockIdx.x, d = threadIdx.x;
  ws[WS_XSA0 + r * DD + d] = ws[WS_X0VEC + d];
}

// --- out[r][d] = scale*(in[r]·W[d,:] + bias[d]) ; 2 rows / block ----------
__global__ __launch_bounds__(256) void k_rowmat2(
    const float* __restrict__ in, const float* __restrict__ W,
    const float* __restrict__ bias, float* __restrict__ out, float scale) {
  int r0 = blockIdx.x * 2, d = threadIdx.x;
  __shared__ float u[2][260];
  u[0][d] = in[r0 * DD + d];
  u[1][d] = in[(r0 + 1) * DD + d];
  __syncthreads();
  float a0 = 0.f, a1 = 0.f;
  const float4* w4 = (const float4*)(W + d * DD);
  const float4* u0 = (const float4*)&u[0][0];
  const float4* u1 = (const float4*)&u[1][0];
#pragma unroll 8
  for (int k4 = 0; k4 < 64; k4++) {
    float4 w = w4[k4], x0 = u0[k4], x1 = u1[k4];
    a0 += x0.x*w.x + x0.y*w.y + x0.z*w.z + x0.w*w.w;
    a1 += x1.x*w.x + x1.y*w.y + x1.z*w.z + x1.w*w.w;
  }
  float b = bias[d];
  out[r0 * DD + d]       = (a0 + b) * scale;
  out[(r0 + 1) * DD + d] = (a1 + b) * scale;
}

// --- one recurrence step --------------------------------------------------
// grid (32 rowgroups, 8 colgroups), 256 thr; block: 16 rows x 32 cols
__global__ __launch_bounds__(256) void k_step(
    const float* __restrict__ xin, const float* __restrict__ wct,
    const float* __restrict__ zeu3, float* __restrict__ xout) {
  int rg = blockIdx.x, cg = blockIdx.y;
  int b = rg >> 2, l0 = (rg & 3) * 16;
  int t = threadIdx.x, cl = t & 31, rs = t >> 5;
  int c = cg * 32 + cl;
  __shared__ float S[18][260];
  const float* xb = xin + b * LL * DD;
  for (int j = 0; j < 18; j++) {
    int l = (l0 + j - 1 + LL) & (LL - 1);
    S[j][t] = xb[l * DD + t];
  }
  __syncthreads();
  float a0 = 0.f, a1 = 0.f;
  const float* wb = wct + c * K3;
#pragma unroll
  for (int p = 0; p < 3; p++) {
    int j0 = rs + ((p == 0) ? 0 : (p == 1) ? 2 : 1);
    const float4* w4 = (const float4*)(wb + p * 256);
    const float4* u0 = (const float4*)&S[j0][0];
    const float4* u1 = (const float4*)&S[j0 + 8][0];
#pragma unroll 8
    for (int k4 = 0; k4 < 64; k4++) {
      float4 w = w4[k4], x0 = u0[k4], x1 = u1[k4];
      a0 += x0.x*w.x + x0.y*w.y + x0.z*w.z + x0.w*w.w;
      a1 += x1.x*w.x + x1.y*w.y + x1.z*w.z + x1.w*w.w;
    }
  }
  int r0 = b * LL + l0 + rs;
  int r1 = r0 + 8;
  xout[r0 * DD + c] = a0 + zeu3[r0 * DD + c];
  xout[r1 * DD + c] = a1 + zeu3[r1 * DD + c];
}

// --- ylog[v] = yvec · embed[v] -------------------------------------------
__global__ __launch_bounds__(256) void k_ylog(
    const float* __restrict__ embed, float* __restrict__ ws) {
  __shared__ float y[DD];
  int t = threadIdx.x;
  y[t] = ws[WS_YVEC + t];
  __syncthreads();
  int w = t >> 6, lane = t & 63;
  for (int i = 0; i < 16; i++) {
    int v = blockIdx.x * 64 + i * 4 + w;
    float p = 0.f;
#pragma unroll
    for (int j = 0; j < 4; j++) p += y[lane + 64*j] * embed[v * DD + lane + 64*j];
    p = waveSum(p);
    if (lane == 0) ws[WS_YLOG + v] = p;
  }
}

// --- ylse = logsumexp(ylog) ----------------------------------------------
__global__ __launch_bounds__(256) void k_ylse(float* __restrict__ ws) {
  int t = threadIdx.x;
  float m = -1e30f, s = 0.f;
  for (int v = t; v < VV; v += 256) {
    float lg = ws[WS_YLOG + v];
    float mn = fmaxf(m, lg);
    s = s * __expf(m - mn) + __expf(lg - mn);
    m = mn;
  }
#pragma unroll
  for (int o = 32; o > 0; o >>= 1) {
    float mo = __shfl_xor(m, o, 64), so = __shfl_xor(s, o, 64);
    float mn = fmaxf(m, mo);
    s = s * __expf(m - mn) + so * __expf(mo - mn);
    m = mn;
  }
  __shared__ float rm[4], rv[4];
  int lane = t & 63, w = t >> 6;
  if (lane == 0) { rm[w] = m; rv[w] = s; }
  __syncthreads();
  if (t == 0) {
    float M = fmaxf(fmaxf(rm[0], rm[1]), fmaxf(rm[2], rm[3]));
    float S = rv[0]*__expf(rm[0]-M) + rv[1]*__expf(rm[1]-M) +
              rv[2]*__expf(rm[2]-M) + rv[3]*__expf(rm[3]-M);
    ws[WS_YLSE] = M + logf(S);
  }
}

// --- sel logits: s0,s1,s2 per row ----------------------------------------
__global__ __launch_bounds__(256) void k_sel(
    const float* __restrict__ xks, float* __restrict__ ws) {
  int row = blockIdx.x * 4 + (threadIdx.x >> 6);
  int lane = threadIdx.x & 63;
  const float* xr = ws + WS_XSA0 + row * DD;
  float a0 = 0.f, a1 = 0.f, a2 = 0.f;
#pragma unroll
  for (int j = 0; j < 4; j++) {
    float xv = xr[lane + 64*j];
    a0 += xv * xks[lane + 64*j];
    a1 += xv * xks[DD + lane + 64*j];
    a2 += xv * ws[WS_YK + lane + 64*j];
  }
  a0 = waveSum(a0); a1 = waveSum(a1); a2 = waveSum(a2);
  if (lane == 0) {
    ws[WS_SEL + row*4 + 0] = a0;
    ws[WS_SEL + row*4 + 1] = a1;
    ws[WS_SEL + row*4 + 2] = a2;
  }
}

// --- head: per (row, vchunk) partial online logsumexp --------------------
// grid (64 rowgroups of 16, 8 vchunks of 512), 256 thr
__global__ __launch_bounds__(256) void k_head(
    const float* __restrict__ embed, float* __restrict__ ws) {
  int rg = blockIdx.x, vc = blockIdx.y;
  int t = threadIdx.x, vl = t & 63, rs = t >> 6;
  __shared__ float U[16][260];
  int row0 = rg * 16;
  const float* src = (row0 < RR) ? (ws + WS_EMIT + row0 * DD)
                                 : (ws + WS_ZE + (row0 - RR) * DD);
  for (int j = 0; j < 16; j++) U[j][t] = src[j * DD + t];
  __syncthreads();
  float m[4], s[4];
#pragma unroll
  for (int q = 0; q < 4; q++) { m[q] = -1e30f; s[q] = 0.f; }
  for (int it = 0; it < 8; it++) {
    int v = vc * 512 + it * 64 + vl;
    const float4* e4 = (const float4*)(embed + v * DD);
    float acc[4] = {0.f, 0.f, 0.f, 0.f};
#pragma unroll 4
    for (int k4 = 0; k4 < 64; k4++) {
      float4 e = e4[k4];
#pragma unroll
      for (int q = 0; q < 4; q++) {
        float4 u = ((const float4*)&U[rs + q*4][0])[k4];
        acc[q] += u.x*e.x + u.y*e.y + u.z*e.z + u.w*e.w;
      }
    }
#pragma unroll
    for (int q = 0; q < 4; q++) {
      float mn = fmaxf(m[q], acc[q]);
      s[q] = s[q] * __expf(m[q] - mn) + __expf(acc[q] - mn);
      m[q] = mn;
    }
  }
#pragma unroll
  for (int o = 32; o > 0; o >>= 1) {
#pragma unroll
    for (int q = 0; q < 4; q++) {
      float mo = __shfl_xor(m[q], o, 64), so = __shfl_xor(s[q], o, 64);
      float mn = fmaxf(m[q], mo);
      s[q] = s[q] * __expf(m[q] - mn) + so * __expf(mo - mn);
      m[q] = mn;
    }
  }
  if (vl == 0) {
#pragma unroll
    for (int q = 0; q < 4; q++) {
      int row = row0 + rs + q*4;
      ws[WS_HPART + (row*8 + vc)*2]     = m[q];
      ws[WS_HPART + (row*8 + vc)*2 + 1] = s[q];
    }
  }
}

// --- target logits: dot(cand_row, embed[x]) ------------------------------
__global__ __launch_bounds__(256) void k_tgt(
    const int* __restrict__ x, const float* __restrict__ embed,
    float* __restrict__ ws) {
  int row = blockIdx.x * 4 + (threadIdx.x >> 6);
  int lane = threadIdx.x & 63;
  int r5 = row & (RR - 1);
  const float* vec = (row < RR) ? (ws + WS_EMIT + r5 * DD) : (ws + WS_ZE + r5 * DD);
  int v = x[r5];
  float p = 0.f;
#pragma unroll
  for (int j = 0; j < 4; j++) p += vec[lane + 64*j] * embed[v * DD + lane + 64*j];
  p = waveSum(p);
  if (lane == 0) ws[WS_TGT + row] = p;
}

// --- combine per-chunk partials into per-row LSE -------------------------
__global__ __launch_bounds__(256) void k_comb(float* __restrict__ ws) {
  int row = blockIdx.x * 256 + threadIdx.x;
  float mm[8], sv[8];
  float M = -1e30f;
#pragma unroll
  for (int c = 0; c < 8; c++) {
    mm[c] = ws[WS_HPART + (row*8 + c)*2];
    sv[c] = ws[WS_HPART + (row*8 + c)*2 + 1];
    M = fmaxf(M, mm[c]);
  }
  float S = 0.f;
#pragma unroll
  for (int c = 0; c < 8; c++) S += sv[c] * __expf(mm[c] - M);
  ws[WS_LSE + row] = M + logf(S);
}

// --- final: mixture prob at target, sqrt, mean over L, negate ------------
__global__ __launch_bounds__(64) void k_final(
    const int* __restrict__ x, float* __restrict__ ws, float* __restrict__ out) {
  int b = blockIdx.x, l = threadIdx.x, r = b * 64 + l;
  float s0 = ws[WS_SEL + r*4], s1 = ws[WS_SEL + r*4+1], s2 = ws[WS_SEL + r*4+2];
  float mx = fmaxf(s0, fmaxf(s1, s2));
  float den = expf(s0 - mx) + expf(s1 - mx) + 64.f * expf(s2 - mx);
  float lsel = mx + logf(den);
  int xv = x[r];
  float P0 = expf(s0 - lsel + ws[WS_TGT + r]      - ws[WS_LSE + r]);
  float P1 = expf(s1 - lsel + ws[WS_TGT + RR + r] - ws[WS_LSE + RR + r]);
  float Py = expf(s2 - lsel + ws[WS_YLOG + xv]    - ws[WS_YLSE]);
  float cent = sqrtf(P0 + P1 + 64.f * Py);
  float sum = waveSum(cent);
  if (l == 0) out[b] = -(sum * (1.0f / 64.f));
}

extern "C" void kernel_launch(void* const* d_in, const int* in_sizes, int n_in,
                              void* d_out, int out_size, void* d_ws, size_t ws_size,
                              hipStream_t stream) {
  (void)in_sizes; (void)n_in; (void)out_size; (void)ws_size;
  const int*   x     = (const int*)d_in[0];
  const int*   z     = (const int*)d_in[1];
  const float* embed = (const float*)d_in[2];
  const float* initw = (const float*)d_in[3];
  const float* tw    = (const float*)d_in[4];
  const float* tb    = (const float*)d_in[5];
  const float* cw    = (const float*)d_in[6];
  const float* uw    = (const float*)d_in[7];
  const float* xks   = (const float*)d_in[8];
  const float* xkdw  = (const float*)d_in[9];
  const float* xkdb  = (const float*)d_in[10];
  const float* emiw  = (const float*)d_in[11];
  const float* emib  = (const float*)d_in[12];
  float* ws  = (float*)d_ws;
  float* out = (float*)d_out;

  hipLaunchKernelGGL(k_norm_rows, dim3(RR + 2), dim3(256), 0, stream, z, embed, initw, ws);
  hipLaunchKernelGGL(k_build_w,   dim3(256),    dim3(256), 0, stream, tw, cw, ws + WS_WCT);
  hipLaunchKernelGGL(k_yk,        dim3(1),      dim3(256), 0, stream, xkdw, xkdb, ws);
  hipLaunchKernelGGL(k_bcast,     dim3(512),    dim3(256), 0, stream, ws);
  hipLaunchKernelGGL(k_rowmat2,   dim3(256),    dim3(256), 0, stream,
                     ws + WS_ZE, uw, tb, ws + WS_ZEU3, 1.0f / 3.0f);
  hipLaunchKernelGGL(k_ylog,      dim3(64),     dim3(256), 0, stream, embed, ws);
  hipLaunchKernelGGL(k_ylse,      dim3(1),      dim3(256), 0, stream, ws);

  for (int t = 0; t < 64; t++) {
    const float* xin = ws + ((t & 1) ? WS_XSA1 : WS_XSA0);
    float*       xo  = ws + ((t & 1) ? WS_XSA0 : WS_XSA1);
    hipLaunchKernelGGL(k_step, dim3(32, 8), dim3(256), 0, stream,
                       xin, ws + WS_WCT, ws + WS_ZEU3, xo);
  }

  hipLaunchKernelGGL(k_rowmat2, dim3(256), dim3(256), 0, stream,
                     ws + WS_XSA0, emiw, emib, ws + WS_EMIT, 1.0f);
  hipLaunchKernelGGL(k_sel,  dim3(128),      dim3(256), 0, stream, xks, ws);
  hipLaunchKernelGGL(k_head, dim3(64, 8),    dim3(256), 0, stream, embed, ws);
  hipLaunchKernelGGL(k_tgt,  dim3(256),      dim3(256), 0, stream, x, embed, ws);
  hipLaunchKernelGGL(k_comb, dim3(4),        dim3(256), 0, stream, ws);
  hipLaunchKernelGGL(k_final, dim3(8),       dim3(64),  0, stream, x, ws, out);
}